// Round 6
// baseline (187.437 us; speedup 1.0000x reference)
//
#include <hip/hip_runtime.h>

#define N_NODES 50000
#define N_EDGES 800000
#define NBKT 782          // dest buckets of 64 nodes
#define BINB 782          // binning blocks (1024 edges each, 4/thread)
#define BCAP 1792         // staging cap per bucket (mean 1024 + 24 sigma)
#define UTS 136           // LDS tile row stride (halves); breaks stride-128 conflicts

typedef __attribute__((ext_vector_type(4))) float floatx4;
typedef __attribute__((ext_vector_type(8))) _Float16 half8;
typedef __attribute__((ext_vector_type(4))) _Float16 half4;
typedef __attribute__((ext_vector_type(2))) _Float16 half2v;

// ---- workspace layout (bytes) ----
#define O_GF    0UL          // int[NBKT*16] bucket fills, one per 64B line (padded)
#define O_W1    50048UL      // f16[128*128] (transposed [n][k])
#define O_W2    82816UL      // f16[64*128]  (transposed [n][k])
#define O_STG   99200UL      // u32 staging[NBKT*BCAP] = 5.6MB
#define O_H16   5704576UL    // f16[N*128] dinv-prescaled h
// end: 18504576 bytes (< proven 29.45MB footprint)

// Direct-global-atomic binning: each edge takes a slot in its 64-node bucket
// via one padded global atomicAdd (order within a bucket is irrelevant to the
// consumers, which re-histogram locally). No LDS phase, no barriers.
// 782 blocks -> ~3 blocks/CU (vs 196 two-phase blocks at <1/CU before).
// Blocks [BINB, BINB+96) transpose the weights to f16 (independent riders).
__global__ __launch_bounds__(256) void k_bin(const int* __restrict__ ei,
                                             int* __restrict__ gfill,
                                             unsigned* __restrict__ staging,
                                             const float* __restrict__ Wg,
                                             const float* __restrict__ Wf,
                                             _Float16* __restrict__ W1,
                                             _Float16* __restrict__ W2) {
    int b = blockIdx.x, t = threadIdx.x;
    if (b >= BINB) {                               // weight-transpose rider blocks
        int wb = b - BINB;
        if (wb < 64) {
            int i = wb * 256 + t;                  // W1: 16384 elems
            int n = i >> 7, k = i & 127;
            W1[i] = (_Float16)Wg[k * 128 + n];
        } else {
            int i = (wb - 64) * 256 + t;           // W2: 8192 elems
            int n = i >> 7, k = i & 127;
            W2[i] = (_Float16)Wf[k * 64 + n];
        }
        return;
    }
    __shared__ int s_i64;
    if (t < 64) {                                  // wave 0: int64 probe
        unsigned w = ((const unsigned*)ei)[2 * t + 1];
        unsigned long long m = __ballot(w == 0u);
        if (t == 0) s_i64 = (__popcll(m) >= 60) ? 1 : 0;
    }
    __syncthreads();
    bool i64 = s_i64 != 0;
    int e0 = b * 1024 + t * 4;                     // 4 edges per thread
    int sv[4], dvv[4];
    if (i64) {
        const int4* ps = (const int4*)(ei) + (e0 >> 1);
        const int4* pd = (const int4*)(ei + 2 * (size_t)N_EDGES) + (e0 >> 1);
#pragma unroll
        for (int g = 0; g < 2; ++g) {
            if (e0 + 2 * g < N_EDGES) {
                int4 s4 = ps[g], d4 = pd[g];
                sv[2 * g] = s4.x; sv[2 * g + 1] = s4.z;
                dvv[2 * g] = d4.x; dvv[2 * g + 1] = d4.z;
            } else { dvv[2 * g] = -1; dvv[2 * g + 1] = -1; }
        }
    } else {
        if (e0 < N_EDGES) {
            int4 s4 = ((const int4*)(ei))[e0 >> 2];
            int4 d4 = ((const int4*)(ei + (size_t)N_EDGES))[e0 >> 2];
            sv[0] = s4.x; sv[1] = s4.y; sv[2] = s4.z; sv[3] = s4.w;
            dvv[0] = d4.x; dvv[1] = d4.y; dvv[2] = d4.z; dvv[3] = d4.w;
        } else { dvv[0] = -1; dvv[1] = -1; dvv[2] = -1; dvv[3] = -1; }
    }
#pragma unroll
    for (int j = 0; j < 4; ++j) {
        int d = dvv[j];
        if (d >= 0 && e0 + j < N_EDGES) {
            int bkt = d >> 6;                      // 64-node bucket
            unsigned pk = (unsigned)sv[j] | ((unsigned)(d & 63) << 16);
            int pos = atomicAdd(&gfill[bkt * 16], 1);   // padded: 1 counter/line
            if (pos < BCAP) staging[(size_t)bkt * BCAP + pos] = pk;
        }
    }
}

// h16 = f16(h * dinv[row]). dinv computed LOCALLY from the 2 bucket runs
// covering this block's 128 rows (deg histogram of staged tags).
__global__ __launch_bounds__(256) void k_conv(const float* __restrict__ h,
                                              const int* __restrict__ gfill,
                                              const unsigned* __restrict__ staging,
                                              _Float16* __restrict__ h16) {
    __shared__ int deg[128];
    __shared__ float sdv[128];
    int b = blockIdx.x, t = threadIdx.x;
    int nb = b * 128;
    int nn = min(128, N_NODES - nb);
    if (nn <= 0) return;
    if (t < 128) deg[t] = 0;
    __syncthreads();
#pragma unroll
    for (int kb = 0; kb < 2; ++kb) {
        int gb = b * 2 + kb;                       // grid 391 -> gb <= 781 < NBKT
        int cnt = min(gfill[gb * 16], BCAP);
        const unsigned* st = staging + (size_t)gb * BCAP;
        for (int i = t; i < cnt; i += 256)
            atomicAdd(&deg[kb * 64 + (st[i] >> 16)], 1);
    }
    __syncthreads();
    if (t < 128) sdv[t] = rsqrtf((float)(deg[t] + 1));   // +1 = self-loop
    __syncthreads();
    const floatx4* src = (const floatx4*)(h + (size_t)nb * 128);
    half4* dst = (half4*)(h16 + (size_t)nb * 128);
    int nq = nn * 32;                              // 32 float4 per 128-wide row
    for (int i = t; i < nq; i += 256) {
        floatx4 v = src[i];
        float s = sdv[i >> 5];
        half4 o;
        o[0] = (_Float16)(v[0] * s); o[1] = (_Float16)(v[1] * s);
        o[2] = (_Float16)(v[2] * s); o[3] = (_Float16)(v[3] * s);
        dst[i] = o;
    }
}

// Fused aggregate + double GEMM. Block = 16 consecutive nodes (grid 3125).
// Prologue builds per-node edge lists in LDS from the bucket staging.
// R5-proven form — only the gfill indexing (padded) changed.
__global__ __launch_bounds__(256, 8) void k_aggF(const _Float16* __restrict__ h16,
                                                 const int* __restrict__ gfill,
                                                 const unsigned* __restrict__ staging,
                                                 const _Float16* __restrict__ W1,
                                                 const _Float16* __restrict__ W2,
                                                 const float* __restrict__ bg,
                                                 const float* __restrict__ bfc,
                                                 float* __restrict__ out) {
    __shared__ _Float16 ut[16 * UTS];
    __shared__ _Float16 z[16 * UTS];
    __shared__ unsigned short se[BCAP];            // 3.5KB per-node lists
    __shared__ int deg16[16], seg16[16], cur16[16];
    __shared__ float sdv16[16];
    int t = threadIdx.x;
    int wave = t >> 6;
    int lane = t & 63;
    int nb = blockIdx.x * 16;
    int bkt = blockIdx.x >> 2;                     // 64-node bucket
    unsigned lo = (unsigned)(blockIdx.x & 3) * 16; // our 16-tag window
    int cnt = min(gfill[bkt * 16], BCAP);
    if (t < 16) deg16[t] = 0;
    __syncthreads();
    const unsigned* st = staging + (size_t)bkt * BCAP;
    unsigned held[7];                              // static-indexed (no scratch)
#pragma unroll
    for (int r = 0; r < 7; ++r) {
        int i = t + r * 256;
        unsigned p = 0xFFFFFFFFu;
        if (i < cnt) p = st[i];
        unsigned tg = p >> 16;
        if (tg - lo < 16u) atomicAdd(&deg16[tg - lo], 1);
        else p = 0xFFFFFFFFu;
        held[r] = p;
    }
    __syncthreads();
    if (t == 0) {
        int s = 0;
#pragma unroll
        for (int k = 0; k < 16; ++k) { seg16[k] = s; cur16[k] = s; s += deg16[k]; }
    }
    if (t < 16) sdv16[t] = rsqrtf((float)(deg16[t] + 1));  // matches k_conv bit-exact
    __syncthreads();
#pragma unroll
    for (int r = 0; r < 7; ++r) {
        unsigned p = held[r];
        if (p != 0xFFFFFFFFu) {
            int rk = atomicAdd(&cur16[(p >> 16) - lo], 1);
            if (rk < BCAP) se[rk] = (unsigned short)(p & 0xffffu);
        }
    }
    __syncthreads();
    for (int q = 0; q < 4; ++q) {
        int tag = wave * 4 + q;
        int node = nb + tag;
        int p0 = seg16[tag];
        int p1 = p0 + deg16[tag];
        half2v us = *(const half2v*)(h16 + (size_t)node * 128 + lane * 2);
        float a0 = (float)us[0], a1 = (float)us[1];           // self-loop
        for (int base = p0; base < p1; base += 64) {
            int c = p1 - base; if (c > 64) c = 64;
            int idx = 0;
            if (lane < c) idx = se[base + lane];
            int j = 0;
            for (; j + 8 <= c; j += 8) {
                int s0 = __shfl(idx, j),     s1 = __shfl(idx, j + 1);
                int s2 = __shfl(idx, j + 2), s3 = __shfl(idx, j + 3);
                int s4 = __shfl(idx, j + 4), s5 = __shfl(idx, j + 5);
                int s6 = __shfl(idx, j + 6), s7 = __shfl(idx, j + 7);
                half2v u0 = *(const half2v*)(h16 + (size_t)s0 * 128 + lane * 2);
                half2v u1 = *(const half2v*)(h16 + (size_t)s1 * 128 + lane * 2);
                half2v u2 = *(const half2v*)(h16 + (size_t)s2 * 128 + lane * 2);
                half2v u3 = *(const half2v*)(h16 + (size_t)s3 * 128 + lane * 2);
                half2v u4 = *(const half2v*)(h16 + (size_t)s4 * 128 + lane * 2);
                half2v u5 = *(const half2v*)(h16 + (size_t)s5 * 128 + lane * 2);
                half2v u6 = *(const half2v*)(h16 + (size_t)s6 * 128 + lane * 2);
                half2v u7 = *(const half2v*)(h16 + (size_t)s7 * 128 + lane * 2);
                a0 += (float)u0[0] + (float)u1[0] + (float)u2[0] + (float)u3[0]
                    + (float)u4[0] + (float)u5[0] + (float)u6[0] + (float)u7[0];
                a1 += (float)u0[1] + (float)u1[1] + (float)u2[1] + (float)u3[1]
                    + (float)u4[1] + (float)u5[1] + (float)u6[1] + (float)u7[1];
            }
            for (; j + 4 <= c; j += 4) {
                int s0 = __shfl(idx, j),     s1 = __shfl(idx, j + 1);
                int s2 = __shfl(idx, j + 2), s3 = __shfl(idx, j + 3);
                half2v u0 = *(const half2v*)(h16 + (size_t)s0 * 128 + lane * 2);
                half2v u1 = *(const half2v*)(h16 + (size_t)s1 * 128 + lane * 2);
                half2v u2 = *(const half2v*)(h16 + (size_t)s2 * 128 + lane * 2);
                half2v u3 = *(const half2v*)(h16 + (size_t)s3 * 128 + lane * 2);
                a0 += (float)u0[0] + (float)u1[0] + (float)u2[0] + (float)u3[0];
                a1 += (float)u0[1] + (float)u1[1] + (float)u2[1] + (float)u3[1];
            }
            for (; j < c; ++j) {
                int s = __shfl(idx, j);
                half2v uu = *(const half2v*)(h16 + (size_t)s * 128 + lane * 2);
                a0 += (float)uu[0]; a1 += (float)uu[1];
            }
        }
        float sc = sdv16[tag];
        int r = wave * 4 + q;
        ut[r * UTS + lane * 2]     = (_Float16)(a0 * sc);
        ut[r * UTS + lane * 2 + 1] = (_Float16)(a1 * sc);
    }
    __syncthreads();
    int quad = lane >> 4, l15 = lane & 15;
    half8 a[4];
#pragma unroll
    for (int kk = 0; kk < 4; ++kk)
        a[kk] = *(const half8*)(ut + l15 * UTS + kk * 32 + quad * 8);
#pragma unroll
    for (int tt = 0; tt < 2; ++tt) {               // GEMM1: wave does 2 of 8 n-tiles
        floatx4 acc = {0.f, 0.f, 0.f, 0.f};
        int n = (wave * 2 + tt) * 16 + l15;
#pragma unroll
        for (int kk = 0; kk < 4; ++kk) {
            half8 bb = *(const half8*)(W1 + n * 128 + kk * 32 + quad * 8);
            acc = __builtin_amdgcn_mfma_f32_16x16x32_f16(a[kk], bb, acc, 0, 0, 0);
        }
        float bias = bg[n];
#pragma unroll
        for (int i = 0; i < 4; ++i)
            z[(quad * 4 + i) * UTS + n] = (_Float16)fmaxf(acc[i] + bias, 0.f);
    }
    __syncthreads();
    half8 a2[4];
#pragma unroll
    for (int kk = 0; kk < 4; ++kk)
        a2[kk] = *(const half8*)(z + l15 * UTS + kk * 32 + quad * 8);
    {                                               // GEMM2: wave does 1 of 4 n-tiles
        floatx4 acc = {0.f, 0.f, 0.f, 0.f};
        int n = wave * 16 + l15;
#pragma unroll
        for (int kk = 0; kk < 4; ++kk) {
            half8 bb = *(const half8*)(W2 + n * 128 + kk * 32 + quad * 8);
            acc = __builtin_amdgcn_mfma_f32_16x16x32_f16(a2[kk], bb, acc, 0, 0, 0);
        }
        float bias = bfc[n];
#pragma unroll
        for (int i = 0; i < 4; ++i)
            out[(size_t)(nb + quad * 4 + i) * 64 + n] = acc[i] + bias;
    }
}

extern "C" void kernel_launch(void* const* d_in, const int* in_sizes, int n_in,
                              void* d_out, int out_size, void* d_ws, size_t ws_size,
                              hipStream_t stream) {
    (void)in_sizes; (void)n_in; (void)out_size; (void)ws_size;
    const float* h  = (const float*)d_in[0];
    const int*   ei = (const int*)d_in[1];
    const float* Wg = (const float*)d_in[2];
    const float* bg = (const float*)d_in[3];
    const float* Wf = (const float*)d_in[4];
    const float* bf = (const float*)d_in[5];
    float* out = (float*)d_out;

    char* ws = (char*)d_ws;
    int*      gfill = (int*)(ws + O_GF);
    _Float16* W1    = (_Float16*)(ws + O_W1);
    _Float16* W2    = (_Float16*)(ws + O_W2);
    unsigned* staging = (unsigned*)(ws + O_STG);
    _Float16* h16   = (_Float16*)(ws + O_H16);

    hipMemsetAsync(gfill, 0, NBKT * 16 * sizeof(int), stream);
    k_bin<<<BINB + 96, 256, 0, stream>>>(ei, gfill, staging, Wg, Wf, W1, W2);
    k_conv<<<(N_NODES + 127) / 128, 256, 0, stream>>>(h, gfill, staging, h16);
    k_aggF<<<N_NODES / 16, 256, 0, stream>>>(h16, gfill, staging,
                                             W1, W2, bg, bf, out);
}

// Round 7
// 154.752 us; speedup vs baseline: 1.2112x; 1.2112x over previous
//
#include <hip/hip_runtime.h>

#define N_NODES 50000
#define N_EDGES 800000
#define NBKT 782          // dest buckets of 64 nodes
#define BINB 196          // binning blocks (4096 edges each) — R5-proven form
#define BCAP 1792         // staging cap per bucket (mean 1024 + 24 sigma)
#define UTS 136           // LDS tile row stride (halves); breaks stride-128 conflicts

typedef __attribute__((ext_vector_type(4))) float floatx4;
typedef __attribute__((ext_vector_type(8))) _Float16 half8;
typedef __attribute__((ext_vector_type(4))) _Float16 half4;
typedef __attribute__((ext_vector_type(2))) _Float16 half2v;

// ---- workspace layout (bytes) ---- (R5-proven)
#define O_GF    0UL          // int[NBKT] bucket fill counts
#define O_W1    3200UL       // f16[128*128] (transposed [n][k])
#define O_W2    35968UL      // f16[64*128]  (transposed [n][k])
#define O_STG   52480UL      // u32 staging[NBKT*BCAP] = 5.6MB
#define O_H16   5657856UL    // f16[N*128] dinv-prescaled h
// end: 18457856 bytes (< proven 29.45MB footprint)

// Bin edges by dest>>6 into per-bucket staging runs. R5-proven two-phase form:
// LDS rank assignment + per-(block,bucket) aggregated global base claim.
// (R6 lesson: direct per-edge global atomicAdd-with-return serializes ~1000-deep
// per cache line and cost +33us. Keep the two-phase form.)
// Blocks [BINB, BINB+96) transpose the weights to f16 (independent riders).
__global__ __launch_bounds__(256) void k_bin(const int* __restrict__ ei,
                                             int* __restrict__ gfill,
                                             unsigned* __restrict__ staging,
                                             const float* __restrict__ Wg,
                                             const float* __restrict__ Wf,
                                             _Float16* __restrict__ W1,
                                             _Float16* __restrict__ W2) {
    int b = blockIdx.x, t = threadIdx.x;
    if (b >= BINB) {                               // weight-transpose rider blocks
        int wb = b - BINB;
        if (wb < 64) {
            int i = wb * 256 + t;                  // W1: 16384 elems
            int n = i >> 7, k = i & 127;
            W1[i] = (_Float16)Wg[k * 128 + n];
        } else {
            int i = (wb - 64) * 256 + t;           // W2: 8192 elems
            int n = i >> 7, k = i & 127;
            W2[i] = (_Float16)Wf[k * 64 + n];
        }
        return;
    }
    __shared__ int cnt[NBKT];
    __shared__ int gbase[NBKT];
    __shared__ int s_i64;
    if (t < 64) {                                  // wave 0: int64 probe
        unsigned w = ((const unsigned*)ei)[2 * t + 1];
        unsigned long long m = __ballot(w == 0u);
        if (t == 0) s_i64 = (__popcll(m) >= 60) ? 1 : 0;
    }
    for (int i = t; i < NBKT; i += 256) cnt[i] = 0;
    __syncthreads();
    bool i64 = s_i64 != 0;
    int e0 = b * 4096 + t * 16;                    // 16 edges per thread
    int sv[16], dvv[16];
    if (i64) {
        const int4* ps = (const int4*)(ei) + (e0 >> 1);
        const int4* pd = (const int4*)(ei + 2 * (size_t)N_EDGES) + (e0 >> 1);
#pragma unroll
        for (int g = 0; g < 8; ++g) {
            if (e0 + 2 * g < N_EDGES) {
                int4 s4 = ps[g], d4 = pd[g];
                sv[2 * g] = s4.x; sv[2 * g + 1] = s4.z;
                dvv[2 * g] = d4.x; dvv[2 * g + 1] = d4.z;
            } else { dvv[2 * g] = -1; dvv[2 * g + 1] = -1; }
        }
    } else {
        const int4* ps = (const int4*)(ei) + (e0 >> 2);
        const int4* pd = (const int4*)(ei + (size_t)N_EDGES) + (e0 >> 2);
#pragma unroll
        for (int g = 0; g < 4; ++g) {
            if (e0 + 4 * g < N_EDGES) {
                int4 s4 = ps[g], d4 = pd[g];
                sv[4 * g] = s4.x; sv[4 * g + 1] = s4.y; sv[4 * g + 2] = s4.z; sv[4 * g + 3] = s4.w;
                dvv[4 * g] = d4.x; dvv[4 * g + 1] = d4.y; dvv[4 * g + 2] = d4.z; dvv[4 * g + 3] = d4.w;
            } else { dvv[4 * g] = -1; dvv[4 * g + 1] = -1; dvv[4 * g + 2] = -1; dvv[4 * g + 3] = -1; }
        }
    }
    unsigned pk[16]; int rk[16]; short bk[16];
#pragma unroll
    for (int j = 0; j < 16; ++j) {
        int d = dvv[j];
        if (d >= 0 && e0 + j < N_EDGES) {
            int bkt = d >> 6;                      // 64-node bucket
            bk[j] = (short)bkt;
            pk[j] = (unsigned)sv[j] | ((unsigned)(d & 63) << 16);
            rk[j] = atomicAdd(&cnt[bkt], 1);
        } else bk[j] = -1;
    }
    __syncthreads();
    for (int i = t; i < NBKT; i += 256)
        gbase[i] = atomicAdd(&gfill[i], cnt[i]);
    __syncthreads();
#pragma unroll
    for (int j = 0; j < 16; ++j) {
        if (bk[j] >= 0) {
            int pos = gbase[bk[j]] + rk[j];
            if (pos < BCAP) staging[(size_t)bk[j] * BCAP + pos] = pk[j];
        }
    }
}

// h16 = f16(h * dinv[row]). dinv computed LOCALLY from the 2 bucket runs
// covering this block's 128 rows (deg histogram of staged tags). R5-proven.
__global__ __launch_bounds__(256) void k_conv(const float* __restrict__ h,
                                              const int* __restrict__ gfill,
                                              const unsigned* __restrict__ staging,
                                              _Float16* __restrict__ h16) {
    __shared__ int deg[128];
    __shared__ float sdv[128];
    int b = blockIdx.x, t = threadIdx.x;
    int nb = b * 128;
    int nn = min(128, N_NODES - nb);
    if (nn <= 0) return;
    if (t < 128) deg[t] = 0;
    __syncthreads();
#pragma unroll
    for (int kb = 0; kb < 2; ++kb) {
        int gb = b * 2 + kb;                       // grid 391 -> gb <= 781 < NBKT
        int cnt = min(gfill[gb], BCAP);
        const unsigned* st = staging + (size_t)gb * BCAP;
        for (int i = t; i < cnt; i += 256)
            atomicAdd(&deg[kb * 64 + (st[i] >> 16)], 1);
    }
    __syncthreads();
    if (t < 128) sdv[t] = rsqrtf((float)(deg[t] + 1));   // +1 = self-loop
    __syncthreads();
    const floatx4* src = (const floatx4*)(h + (size_t)nb * 128);
    half4* dst = (half4*)(h16 + (size_t)nb * 128);
    int nq = nn * 32;                              // 32 float4 per 128-wide row
    for (int i = t; i < nq; i += 256) {
        floatx4 v = src[i];
        float s = sdv[i >> 5];
        half4 o;
        o[0] = (_Float16)(v[0] * s); o[1] = (_Float16)(v[1] * s);
        o[2] = (_Float16)(v[2] * s); o[3] = (_Float16)(v[3] * s);
        dst[i] = o;
    }
}

// Fused aggregate + double GEMM. Block = 16 consecutive nodes (grid 3125).
// Prologue builds per-node edge lists in LDS from the bucket staging (R5 form).
// NEW this round: half4 2-row gather — lanes 0-31 cover even-j sources, lanes
// 32-63 odd-j, 8B/lane loads (half the VMEM instructions of the half2 form,
// same bytes in flight). shfl_xor(32) merge; lower half stores ut as half4.
__global__ __launch_bounds__(256, 8) void k_aggF(const _Float16* __restrict__ h16,
                                                 const int* __restrict__ gfill,
                                                 const unsigned* __restrict__ staging,
                                                 const _Float16* __restrict__ W1,
                                                 const _Float16* __restrict__ W2,
                                                 const float* __restrict__ bg,
                                                 const float* __restrict__ bfc,
                                                 float* __restrict__ out) {
    __shared__ _Float16 ut[16 * UTS];
    __shared__ _Float16 z[16 * UTS];
    __shared__ unsigned short se[BCAP];            // 3.5KB per-node lists
    __shared__ int deg16[16], seg16[16], cur16[16];
    __shared__ float sdv16[16];
    int t = threadIdx.x;
    int wave = t >> 6;
    int lane = t & 63;
    int l31 = lane & 31;
    bool lowh = lane < 32;
    int nb = blockIdx.x * 16;
    int bkt = blockIdx.x >> 2;                     // 64-node bucket
    unsigned lo = (unsigned)(blockIdx.x & 3) * 16; // our 16-tag window
    int cnt = min(gfill[bkt], BCAP);
    if (t < 16) deg16[t] = 0;
    __syncthreads();
    const unsigned* st = staging + (size_t)bkt * BCAP;
    unsigned held[7];                              // static-indexed (no scratch)
#pragma unroll
    for (int r = 0; r < 7; ++r) {
        int i = t + r * 256;
        unsigned p = 0xFFFFFFFFu;
        if (i < cnt) p = st[i];
        unsigned tg = p >> 16;
        if (tg - lo < 16u) atomicAdd(&deg16[tg - lo], 1);
        else p = 0xFFFFFFFFu;
        held[r] = p;
    }
    __syncthreads();
    if (t == 0) {
        int s = 0;
#pragma unroll
        for (int k = 0; k < 16; ++k) { seg16[k] = s; cur16[k] = s; s += deg16[k]; }
    }
    if (t < 16) sdv16[t] = rsqrtf((float)(deg16[t] + 1));  // matches k_conv bit-exact
    __syncthreads();
#pragma unroll
    for (int r = 0; r < 7; ++r) {
        unsigned p = held[r];
        if (p != 0xFFFFFFFFu) {
            int rk = atomicAdd(&cur16[(p >> 16) - lo], 1);
            if (rk < BCAP) se[rk] = (unsigned short)(p & 0xffffu);
        }
    }
    __syncthreads();
    for (int q = 0; q < 4; ++q) {
        int tag = wave * 4 + q;
        int node = nb + tag;
        int p0 = seg16[tag];
        int p1 = p0 + deg16[tag];
        float a0 = 0.f, a1 = 0.f, a2 = 0.f, a3 = 0.f;
        if (lowh) {                                // self-loop: lower half only
            half4 us = *(const half4*)(h16 + (size_t)node * 128 + l31 * 4);
            a0 = (float)us[0]; a1 = (float)us[1]; a2 = (float)us[2]; a3 = (float)us[3];
        }
        for (int base = p0; base < p1; base += 64) {
            int c = p1 - base; if (c > 64) c = 64;
            int idx = 0;
            if (lane < c) idx = se[base + lane];
            int j = 0;
            for (; j + 8 <= c; j += 8) {           // 4 pair-loads (8 srcs, 2 rows/wave)
                int sA0 = __shfl(idx, j),     sB0 = __shfl(idx, j + 1);
                int sA1 = __shfl(idx, j + 2), sB1 = __shfl(idx, j + 3);
                int sA2 = __shfl(idx, j + 4), sB2 = __shfl(idx, j + 5);
                int sA3 = __shfl(idx, j + 6), sB3 = __shfl(idx, j + 7);
                int r0 = lowh ? sA0 : sB0;
                int r1 = lowh ? sA1 : sB1;
                int r2 = lowh ? sA2 : sB2;
                int r3 = lowh ? sA3 : sB3;
                half4 u0 = *(const half4*)(h16 + (size_t)r0 * 128 + l31 * 4);
                half4 u1 = *(const half4*)(h16 + (size_t)r1 * 128 + l31 * 4);
                half4 u2 = *(const half4*)(h16 + (size_t)r2 * 128 + l31 * 4);
                half4 u3 = *(const half4*)(h16 + (size_t)r3 * 128 + l31 * 4);
                a0 += (float)u0[0] + (float)u1[0] + (float)u2[0] + (float)u3[0];
                a1 += (float)u0[1] + (float)u1[1] + (float)u2[1] + (float)u3[1];
                a2 += (float)u0[2] + (float)u1[2] + (float)u2[2] + (float)u3[2];
                a3 += (float)u0[3] + (float)u1[3] + (float)u2[3] + (float)u3[3];
            }
            for (; j + 2 <= c; j += 2) {           // pair tail
                int sA = __shfl(idx, j), sB = __shfl(idx, j + 1);
                int r0 = lowh ? sA : sB;
                half4 u0 = *(const half4*)(h16 + (size_t)r0 * 128 + l31 * 4);
                a0 += (float)u0[0]; a1 += (float)u0[1];
                a2 += (float)u0[2]; a3 += (float)u0[3];
            }
            if (j < c) {                           // odd final: lower half only
                int s = __shfl(idx, j);
                if (lowh) {
                    half4 u0 = *(const half4*)(h16 + (size_t)s * 128 + l31 * 4);
                    a0 += (float)u0[0]; a1 += (float)u0[1];
                    a2 += (float)u0[2]; a3 += (float)u0[3];
                }
            }
        }
        a0 += __shfl_xor(a0, 32);                  // merge halves (even+odd srcs)
        a1 += __shfl_xor(a1, 32);
        a2 += __shfl_xor(a2, 32);
        a3 += __shfl_xor(a3, 32);
        if (lowh) {
            float sc = sdv16[tag];
            int r = wave * 4 + q;
            half4 o;
            o[0] = (_Float16)(a0 * sc); o[1] = (_Float16)(a1 * sc);
            o[2] = (_Float16)(a2 * sc); o[3] = (_Float16)(a3 * sc);
            *(half4*)(ut + r * UTS + l31 * 4) = o;
        }
    }
    __syncthreads();
    int quad = lane >> 4, l15 = lane & 15;
    half8 a[4];
#pragma unroll
    for (int kk = 0; kk < 4; ++kk)
        a[kk] = *(const half8*)(ut + l15 * UTS + kk * 32 + quad * 8);
#pragma unroll
    for (int tt = 0; tt < 2; ++tt) {               // GEMM1: wave does 2 of 8 n-tiles
        floatx4 acc = {0.f, 0.f, 0.f, 0.f};
        int n = (wave * 2 + tt) * 16 + l15;
#pragma unroll
        for (int kk = 0; kk < 4; ++kk) {
            half8 bb = *(const half8*)(W1 + n * 128 + kk * 32 + quad * 8);
            acc = __builtin_amdgcn_mfma_f32_16x16x32_f16(a[kk], bb, acc, 0, 0, 0);
        }
        float bias = bg[n];
#pragma unroll
        for (int i = 0; i < 4; ++i)
            z[(quad * 4 + i) * UTS + n] = (_Float16)fmaxf(acc[i] + bias, 0.f);
    }
    __syncthreads();
    half8 a2[4];
#pragma unroll
    for (int kk = 0; kk < 4; ++kk)
        a2[kk] = *(const half8*)(z + l15 * UTS + kk * 32 + quad * 8);
    {                                               // GEMM2: wave does 1 of 4 n-tiles
        floatx4 acc = {0.f, 0.f, 0.f, 0.f};
        int n = wave * 16 + l15;
#pragma unroll
        for (int kk = 0; kk < 4; ++kk) {
            half8 bb = *(const half8*)(W2 + n * 128 + kk * 32 + quad * 8);
            acc = __builtin_amdgcn_mfma_f32_16x16x32_f16(a2[kk], bb, acc, 0, 0, 0);
        }
        float bias = bfc[n];
#pragma unroll
        for (int i = 0; i < 4; ++i)
            out[(size_t)(nb + quad * 4 + i) * 64 + n] = acc[i] + bias;
    }
}

extern "C" void kernel_launch(void* const* d_in, const int* in_sizes, int n_in,
                              void* d_out, int out_size, void* d_ws, size_t ws_size,
                              hipStream_t stream) {
    (void)in_sizes; (void)n_in; (void)out_size; (void)ws_size;
    const float* h  = (const float*)d_in[0];
    const int*   ei = (const int*)d_in[1];
    const float* Wg = (const float*)d_in[2];
    const float* bg = (const float*)d_in[3];
    const float* Wf = (const float*)d_in[4];
    const float* bf = (const float*)d_in[5];
    float* out = (float*)d_out;

    char* ws = (char*)d_ws;
    int*      gfill = (int*)(ws + O_GF);
    _Float16* W1    = (_Float16*)(ws + O_W1);
    _Float16* W2    = (_Float16*)(ws + O_W2);
    unsigned* staging = (unsigned*)(ws + O_STG);
    _Float16* h16   = (_Float16*)(ws + O_H16);

    hipMemsetAsync(gfill, 0, NBKT * sizeof(int), stream);
    k_bin<<<BINB + 96, 256, 0, stream>>>(ei, gfill, staging, Wg, Wf, W1, W2);
    k_conv<<<(N_NODES + 127) / 128, 256, 0, stream>>>(h, gfill, staging, h16);
    k_aggF<<<N_NODES / 16, 256, 0, stream>>>(h16, gfill, staging,
                                             W1, W2, bg, bf, out);
}

// Round 8
// 151.581 us; speedup vs baseline: 1.2366x; 1.0209x over previous
//
#include <hip/hip_runtime.h>

#define N_NODES 50000
#define N_EDGES 800000
#define NBKT 782          // dest buckets of 64 nodes
#define BINB 196          // binning blocks (4096 edges each) — R5-proven form
#define CASTB 391         // h->f16 cast rider blocks (128 rows each)
#define BCAP 1792         // staging cap per bucket (mean 1024 + 24 sigma)
#define UTS 136           // LDS tile row stride (halves); breaks stride-128 conflicts

typedef __attribute__((ext_vector_type(4))) float floatx4;
typedef __attribute__((ext_vector_type(8))) _Float16 half8;
typedef __attribute__((ext_vector_type(4))) _Float16 half4;
typedef __attribute__((ext_vector_type(2))) _Float16 half2v;

// ---- workspace layout (bytes) ----
#define O_GF    0UL          // int[NBKT] bucket fill counts
#define O_DEG   3200UL       // int[N] in-degree (excl self), from k_deg
#define O_W1    203264UL     // f16[128*128] (transposed [n][k])
#define O_W2    236032UL     // f16[64*128]  (transposed [n][k])
#define O_STG   252416UL     // u32 staging[NBKT*BCAP] = 5.6MB
#define O_H16   5857792UL    // f16[N*128] UNSCALED f16 cast of h
// end: 18657792 bytes (< proven 29.45MB footprint)

// Bin edges by dest>>6 into per-bucket staging runs. R5-proven two-phase core.
// Riders: [BINB,BINB+96) W transpose; [BINB+96,BINB+96+CASTB) unscaled h->f16
// cast (needs no deg -> runs CONCURRENT with binning, filling idle CUs).
__global__ __launch_bounds__(256) void k_bin(const int* __restrict__ ei,
                                             const float* __restrict__ h,
                                             int* __restrict__ gfill,
                                             unsigned* __restrict__ staging,
                                             const float* __restrict__ Wg,
                                             const float* __restrict__ Wf,
                                             _Float16* __restrict__ W1,
                                             _Float16* __restrict__ W2,
                                             _Float16* __restrict__ h16) {
    int b = blockIdx.x, t = threadIdx.x;
    if (b >= BINB + 96) {                          // h cast riders (unscaled)
        int wb = b - (BINB + 96);
        int nb = wb * 128;
        int nn = min(128, N_NODES - nb);
        if (nn <= 0) return;
        const floatx4* src = (const floatx4*)(h + (size_t)nb * 128);
        half4* dst = (half4*)(h16 + (size_t)nb * 128);
        int nq = nn * 32;
        for (int i = t; i < nq; i += 256) {
            floatx4 v = src[i];
            half4 o;
            o[0] = (_Float16)v[0]; o[1] = (_Float16)v[1];
            o[2] = (_Float16)v[2]; o[3] = (_Float16)v[3];
            dst[i] = o;
        }
        return;
    }
    if (b >= BINB) {                               // weight-transpose riders
        int wb = b - BINB;
        if (wb < 64) {
            int i = wb * 256 + t;                  // W1: 16384 elems
            int n = i >> 7, k = i & 127;
            W1[i] = (_Float16)Wg[k * 128 + n];
        } else {
            int i = (wb - 64) * 256 + t;           // W2: 8192 elems
            int n = i >> 7, k = i & 127;
            W2[i] = (_Float16)Wf[k * 64 + n];
        }
        return;
    }
    __shared__ int cnt[NBKT];
    __shared__ int gbase[NBKT];
    __shared__ int s_i64;
    if (t < 64) {                                  // wave 0: int64 probe
        unsigned w = ((const unsigned*)ei)[2 * t + 1];
        unsigned long long m = __ballot(w == 0u);
        if (t == 0) s_i64 = (__popcll(m) >= 60) ? 1 : 0;
    }
    for (int i = t; i < NBKT; i += 256) cnt[i] = 0;
    __syncthreads();
    bool i64 = s_i64 != 0;
    int e0 = b * 4096 + t * 16;                    // 16 edges per thread
    int sv[16], dvv[16];
    if (i64) {
        const int4* ps = (const int4*)(ei) + (e0 >> 1);
        const int4* pd = (const int4*)(ei + 2 * (size_t)N_EDGES) + (e0 >> 1);
#pragma unroll
        for (int g = 0; g < 8; ++g) {
            if (e0 + 2 * g < N_EDGES) {
                int4 s4 = ps[g], d4 = pd[g];
                sv[2 * g] = s4.x; sv[2 * g + 1] = s4.z;
                dvv[2 * g] = d4.x; dvv[2 * g + 1] = d4.z;
            } else { dvv[2 * g] = -1; dvv[2 * g + 1] = -1; }
        }
    } else {
        const int4* ps = (const int4*)(ei) + (e0 >> 2);
        const int4* pd = (const int4*)(ei + (size_t)N_EDGES) + (e0 >> 2);
#pragma unroll
        for (int g = 0; g < 4; ++g) {
            if (e0 + 4 * g < N_EDGES) {
                int4 s4 = ps[g], d4 = pd[g];
                sv[4 * g] = s4.x; sv[4 * g + 1] = s4.y; sv[4 * g + 2] = s4.z; sv[4 * g + 3] = s4.w;
                dvv[4 * g] = d4.x; dvv[4 * g + 1] = d4.y; dvv[4 * g + 2] = d4.z; dvv[4 * g + 3] = d4.w;
            } else { dvv[4 * g] = -1; dvv[4 * g + 1] = -1; dvv[4 * g + 2] = -1; dvv[4 * g + 3] = -1; }
        }
    }
    unsigned pk[16]; int rk[16]; short bk[16];
#pragma unroll
    for (int j = 0; j < 16; ++j) {
        int d = dvv[j];
        if (d >= 0 && e0 + j < N_EDGES) {
            int bkt = d >> 6;                      // 64-node bucket
            bk[j] = (short)bkt;
            pk[j] = (unsigned)sv[j] | ((unsigned)(d & 63) << 16);
            rk[j] = atomicAdd(&cnt[bkt], 1);
        } else bk[j] = -1;
    }
    __syncthreads();
    for (int i = t; i < NBKT; i += 256)
        gbase[i] = atomicAdd(&gfill[i], cnt[i]);
    __syncthreads();
#pragma unroll
    for (int j = 0; j < 16; ++j) {
        if (bk[j] >= 0) {
            int pos = gbase[bk[j]] + rk[j];
            if (pos < BCAP) staging[(size_t)bk[j] * BCAP + pos] = pk[j];
        }
    }
}

// In-degree per node from staged tags (replaces k_conv on the serial path;
// ~3.2MB read + 200KB write, ~4-5us).
__global__ __launch_bounds__(256) void k_deg(const int* __restrict__ gfill,
                                             const unsigned* __restrict__ staging,
                                             int* __restrict__ deg_g) {
    __shared__ int deg[128];
    int b = blockIdx.x, t = threadIdx.x;
    int nb = b * 128;
    int nn = min(128, N_NODES - nb);
    if (nn <= 0) return;
    if (t < 128) deg[t] = 0;
    __syncthreads();
#pragma unroll
    for (int kb = 0; kb < 2; ++kb) {
        int gb = b * 2 + kb;                       // gb <= 781 < NBKT
        int cnt = min(gfill[gb], BCAP);
        const unsigned* st = staging + (size_t)gb * BCAP;
        for (int i = t; i < cnt; i += 256)
            atomicAdd(&deg[kb * 64 + (st[i] >> 16)], 1);
    }
    __syncthreads();
    if (t < nn) deg_g[nb + t] = deg[t];
}

// Fused aggregate + double GEMM. Block = 16 consecutive nodes (grid 3125).
// Prologue builds per-node edge lists in LDS, packing (deg[src]<<16)|src so
// the gather loop applies w = rsqrt(deg+1) per edge via fma (h16 is unscaled).
// Gather core is the R5-proven half2 8-deep form (R7's half4 was -1.5us).
__global__ __launch_bounds__(256, 8) void k_aggF(const _Float16* __restrict__ h16,
                                                 const int* __restrict__ gfill,
                                                 const unsigned* __restrict__ staging,
                                                 const int* __restrict__ deg_g,
                                                 const _Float16* __restrict__ W1,
                                                 const _Float16* __restrict__ W2,
                                                 const float* __restrict__ bg,
                                                 const float* __restrict__ bfc,
                                                 float* __restrict__ out) {
    __shared__ _Float16 ut[16 * UTS];
    __shared__ _Float16 z[16 * UTS];
    __shared__ unsigned se32[BCAP];                // 7KB: (deg<<16)|src per edge
    __shared__ int deg16[16], seg16[16], cur16[16];
    __shared__ float sdv16[16];
    int t = threadIdx.x;
    int wave = t >> 6;
    int lane = t & 63;
    int nb = blockIdx.x * 16;
    int bkt = blockIdx.x >> 2;                     // 64-node bucket
    unsigned lo = (unsigned)(blockIdx.x & 3) * 16; // our 16-tag window
    int cnt = min(gfill[bkt], BCAP);
    if (t < 16) deg16[t] = 0;
    __syncthreads();
    const unsigned* st = staging + (size_t)bkt * BCAP;
    unsigned held[7]; int dgv[7];                  // static-indexed (no scratch)
#pragma unroll
    for (int r = 0; r < 7; ++r) {
        int i = t + r * 256;
        unsigned p = 0xFFFFFFFFu;
        if (i < cnt) p = st[i];
        unsigned tg = p >> 16;
        dgv[r] = 0;
        if (tg - lo < 16u) {
            atomicAdd(&deg16[tg - lo], 1);
            dgv[r] = deg_g[p & 0xFFFFu];           // src in-degree (L2-resident)
        } else p = 0xFFFFFFFFu;
        held[r] = p;
    }
    __syncthreads();
    if (t == 0) {
        int s = 0;
#pragma unroll
        for (int k = 0; k < 16; ++k) { seg16[k] = s; cur16[k] = s; s += deg16[k]; }
    }
    if (t < 16) sdv16[t] = rsqrtf((float)(deg16[t] + 1));
    __syncthreads();
#pragma unroll
    for (int r = 0; r < 7; ++r) {
        unsigned p = held[r];
        if (p != 0xFFFFFFFFu) {
            int rk = atomicAdd(&cur16[(p >> 16) - lo], 1);
            if (rk < BCAP) se32[rk] = ((unsigned)dgv[r] << 16) | (p & 0xFFFFu);
        }
    }
    __syncthreads();
    for (int q = 0; q < 4; ++q) {
        int tag = wave * 4 + q;
        int node = nb + tag;
        int p0 = seg16[tag];
        int p1 = p0 + deg16[tag];
        float sc = sdv16[tag];
        half2v us = *(const half2v*)(h16 + (size_t)node * 128 + lane * 2);
        float a0 = (float)us[0] * sc, a1 = (float)us[1] * sc;  // self: h*dinv[node]
        for (int base = p0; base < p1; base += 64) {
            int c = p1 - base; if (c > 64) c = 64;
            int idx = 0;
            if (lane < c) idx = (int)se32[base + lane];
            float wf = rsqrtf((float)((unsigned)idx >> 16) + 1.f); // own edge's w
            int j = 0;
            for (; j + 8 <= c; j += 8) {
                int s0 = __shfl(idx, j),     s1 = __shfl(idx, j + 1);
                int s2 = __shfl(idx, j + 2), s3 = __shfl(idx, j + 3);
                int s4 = __shfl(idx, j + 4), s5 = __shfl(idx, j + 5);
                int s6 = __shfl(idx, j + 6), s7 = __shfl(idx, j + 7);
                float f0 = __shfl(wf, j),     f1 = __shfl(wf, j + 1);
                float f2 = __shfl(wf, j + 2), f3 = __shfl(wf, j + 3);
                float f4 = __shfl(wf, j + 4), f5 = __shfl(wf, j + 5);
                float f6 = __shfl(wf, j + 6), f7 = __shfl(wf, j + 7);
                half2v u0 = *(const half2v*)(h16 + (size_t)(s0 & 0xFFFF) * 128 + lane * 2);
                half2v u1 = *(const half2v*)(h16 + (size_t)(s1 & 0xFFFF) * 128 + lane * 2);
                half2v u2 = *(const half2v*)(h16 + (size_t)(s2 & 0xFFFF) * 128 + lane * 2);
                half2v u3 = *(const half2v*)(h16 + (size_t)(s3 & 0xFFFF) * 128 + lane * 2);
                half2v u4 = *(const half2v*)(h16 + (size_t)(s4 & 0xFFFF) * 128 + lane * 2);
                half2v u5 = *(const half2v*)(h16 + (size_t)(s5 & 0xFFFF) * 128 + lane * 2);
                half2v u6 = *(const half2v*)(h16 + (size_t)(s6 & 0xFFFF) * 128 + lane * 2);
                half2v u7 = *(const half2v*)(h16 + (size_t)(s7 & 0xFFFF) * 128 + lane * 2);
                a0 = fmaf((float)u0[0], f0, a0); a1 = fmaf((float)u0[1], f0, a1);
                a0 = fmaf((float)u1[0], f1, a0); a1 = fmaf((float)u1[1], f1, a1);
                a0 = fmaf((float)u2[0], f2, a0); a1 = fmaf((float)u2[1], f2, a1);
                a0 = fmaf((float)u3[0], f3, a0); a1 = fmaf((float)u3[1], f3, a1);
                a0 = fmaf((float)u4[0], f4, a0); a1 = fmaf((float)u4[1], f4, a1);
                a0 = fmaf((float)u5[0], f5, a0); a1 = fmaf((float)u5[1], f5, a1);
                a0 = fmaf((float)u6[0], f6, a0); a1 = fmaf((float)u6[1], f6, a1);
                a0 = fmaf((float)u7[0], f7, a0); a1 = fmaf((float)u7[1], f7, a1);
            }
            for (; j + 4 <= c; j += 4) {
                int s0 = __shfl(idx, j),     s1 = __shfl(idx, j + 1);
                int s2 = __shfl(idx, j + 2), s3 = __shfl(idx, j + 3);
                float f0 = __shfl(wf, j),     f1 = __shfl(wf, j + 1);
                float f2 = __shfl(wf, j + 2), f3 = __shfl(wf, j + 3);
                half2v u0 = *(const half2v*)(h16 + (size_t)(s0 & 0xFFFF) * 128 + lane * 2);
                half2v u1 = *(const half2v*)(h16 + (size_t)(s1 & 0xFFFF) * 128 + lane * 2);
                half2v u2 = *(const half2v*)(h16 + (size_t)(s2 & 0xFFFF) * 128 + lane * 2);
                half2v u3 = *(const half2v*)(h16 + (size_t)(s3 & 0xFFFF) * 128 + lane * 2);
                a0 = fmaf((float)u0[0], f0, a0); a1 = fmaf((float)u0[1], f0, a1);
                a0 = fmaf((float)u1[0], f1, a0); a1 = fmaf((float)u1[1], f1, a1);
                a0 = fmaf((float)u2[0], f2, a0); a1 = fmaf((float)u2[1], f2, a1);
                a0 = fmaf((float)u3[0], f3, a0); a1 = fmaf((float)u3[1], f3, a1);
            }
            for (; j < c; ++j) {
                int s = __shfl(idx, j);
                float f = __shfl(wf, j);
                half2v uu = *(const half2v*)(h16 + (size_t)(s & 0xFFFF) * 128 + lane * 2);
                a0 = fmaf((float)uu[0], f, a0); a1 = fmaf((float)uu[1], f, a1);
            }
        }
        int r = wave * 4 + q;
        ut[r * UTS + lane * 2]     = (_Float16)(a0 * sc);
        ut[r * UTS + lane * 2 + 1] = (_Float16)(a1 * sc);
    }
    __syncthreads();
    int quad = lane >> 4, l15 = lane & 15;
    half8 a[4];
#pragma unroll
    for (int kk = 0; kk < 4; ++kk)
        a[kk] = *(const half8*)(ut + l15 * UTS + kk * 32 + quad * 8);
#pragma unroll
    for (int tt = 0; tt < 2; ++tt) {               // GEMM1: wave does 2 of 8 n-tiles
        floatx4 acc = {0.f, 0.f, 0.f, 0.f};
        int n = (wave * 2 + tt) * 16 + l15;
#pragma unroll
        for (int kk = 0; kk < 4; ++kk) {
            half8 bb = *(const half8*)(W1 + n * 128 + kk * 32 + quad * 8);
            acc = __builtin_amdgcn_mfma_f32_16x16x32_f16(a[kk], bb, acc, 0, 0, 0);
        }
        float bias = bg[n];
#pragma unroll
        for (int i = 0; i < 4; ++i)
            z[(quad * 4 + i) * UTS + n] = (_Float16)fmaxf(acc[i] + bias, 0.f);
    }
    __syncthreads();
    half8 a2[4];
#pragma unroll
    for (int kk = 0; kk < 4; ++kk)
        a2[kk] = *(const half8*)(z + l15 * UTS + kk * 32 + quad * 8);
    {                                               // GEMM2: wave does 1 of 4 n-tiles
        floatx4 acc = {0.f, 0.f, 0.f, 0.f};
        int n = wave * 16 + l15;
#pragma unroll
        for (int kk = 0; kk < 4; ++kk) {
            half8 bb = *(const half8*)(W2 + n * 128 + kk * 32 + quad * 8);
            acc = __builtin_amdgcn_mfma_f32_16x16x32_f16(a2[kk], bb, acc, 0, 0, 0);
        }
        float bias = bfc[n];
#pragma unroll
        for (int i = 0; i < 4; ++i)
            out[(size_t)(nb + quad * 4 + i) * 64 + n] = acc[i] + bias;
    }
}

extern "C" void kernel_launch(void* const* d_in, const int* in_sizes, int n_in,
                              void* d_out, int out_size, void* d_ws, size_t ws_size,
                              hipStream_t stream) {
    (void)in_sizes; (void)n_in; (void)out_size; (void)ws_size;
    const float* h  = (const float*)d_in[0];
    const int*   ei = (const int*)d_in[1];
    const float* Wg = (const float*)d_in[2];
    const float* bg = (const float*)d_in[3];
    const float* Wf = (const float*)d_in[4];
    const float* bf = (const float*)d_in[5];
    float* out = (float*)d_out;

    char* ws = (char*)d_ws;
    int*      gfill = (int*)(ws + O_GF);
    int*      deg_g = (int*)(ws + O_DEG);
    _Float16* W1    = (_Float16*)(ws + O_W1);
    _Float16* W2    = (_Float16*)(ws + O_W2);
    unsigned* staging = (unsigned*)(ws + O_STG);
    _Float16* h16   = (_Float16*)(ws + O_H16);

    hipMemsetAsync(gfill, 0, NBKT * sizeof(int), stream);
    k_bin<<<BINB + 96 + CASTB, 256, 0, stream>>>(ei, h, gfill, staging,
                                                 Wg, Wf, W1, W2, h16);
    k_deg<<<(N_NODES + 127) / 128, 256, 0, stream>>>(gfill, staging, deg_g);
    k_aggF<<<N_NODES / 16, 256, 0, stream>>>(h16, gfill, staging, deg_g,
                                             W1, W2, bg, bf, out);
}